// Round 1
// baseline (245.354 us; speedup 1.0000x reference)
//
#include <hip/hip_runtime.h>

#define U 128
#define BATCH 2048
#define NL 8
#define NS 8                       /* NS=15 vs 10 bit-identical -> contraction <=0.36; NS=8 residual <1e-3 */
#define DTc 0.1f
#define TENf 10.0f                 /* DT/EPS */
#define INVC (1.0f/11.0f)          /* 1/(1+DT/EPS) */
#define AFACT (0.01f/11.0f)        /* DT^2 / c */
#define AST 264                    /* A-tile LDS stride (u16) */

typedef unsigned short u16;
typedef __attribute__((ext_vector_type(8))) short bf16x8;
typedef __attribute__((ext_vector_type(4))) float f32x4;
#define MFMA16(a,b,c) __builtin_amdgcn_mfma_f32_16x16x32_bf16(a,b,c,0,0,0)

__device__ __forceinline__ float bf2f(u16 h){ return __uint_as_float(((unsigned int)h)<<16); }
__device__ __forceinline__ u16 f2bf(float f){
  unsigned int u = __float_as_uint(f);
  u += 0x7FFFu + ((u >> 16) & 1u);
  return (u16)(u >> 16);
}
__device__ __forceinline__ float fast_tanh(float x){
  float e = __expf(2.0f*x);
  return 1.0f - __fdividef(2.0f, e + 1.0f);
}
__device__ __forceinline__ int detect_md(const u16* x, int* s_bad, int t, int nthr){
  if(t==0) *s_bad = 0;
  __syncthreads();
  int f=0;
  for(int i=t;i<4096;i+=nthr){ float v = bf2f(x[i]); if(!(fabsf(v)<16.0f)) f=1; }
  if(f) atomicOr(s_bad,1);
  __syncthreads();
  return *s_bad ? 0 : 1;   // 1 = bf16 inputs
}
__device__ __forceinline__ bf16x8 ld8f(const float* p){
  float4 f0 = *(const float4*)p, f1 = *(const float4*)(p+4);
  bf16x8 v;
  v[0]=(short)f2bf(f0.x); v[1]=(short)f2bf(f0.y); v[2]=(short)f2bf(f0.z); v[3]=(short)f2bf(f0.w);
  v[4]=(short)f2bf(f1.x); v[5]=(short)f2bf(f1.y); v[6]=(short)f2bf(f1.z); v[7]=(short)f2bf(f1.w);
  return v;
}
// LDS-only barrier: does NOT drain vmcnt, so F-prefetch global loads stay in
// flight across the per-step barrier. Only LDS (At/zh32) crosses waves in the
// main loop -> lgkmcnt(0) is the full hazard set. sched_barrier(0) fences
// compiler motion (guide rule #18).
__device__ __forceinline__ void lgkm_barrier(){
  __builtin_amdgcn_sched_barrier(0);
  asm volatile("s_waitcnt lgkmcnt(0)\n\ts_barrier" ::: "memory");
  __builtin_amdgcn_sched_barrier(0);
}

// ---------------- prepF: fused conv + P + S + Q + R + swizzle, 8 blocks -----
// 512 threads; C(128x128) = A(128xK=128, row-major lda) x B^T (B[n][k], ldb).
// Wave wid owns row-tile wid*16; 8 col-frags per wave.
template<typename EPI>
__device__ __forceinline__ void g128(const u16* __restrict__ A, int lda,
                                     const u16* __restrict__ B, int ldb, EPI epi){
  const int lane = threadIdx.x & 63, wid = threadIdx.x >> 6;
  const int ln = lane & 15, lq = lane >> 4;
  bf16x8 af[4];
  #pragma unroll
  for(int kt=0;kt<4;kt++) af[kt] = *(const bf16x8*)&A[(wid*16+ln)*lda + kt*32 + lq*8];
  #pragma unroll
  for(int c=0;c<8;c++){
    const int n0 = c*16 + ln;
    f32x4 acc = {0,0,0,0};
    #pragma unroll
    for(int kt=0;kt<4;kt++)
      acc = MFMA16(af[kt], *(const bf16x8*)&B[n0*ldb + kt*32 + lq*8], acc);
    epi(acc, wid*16 + lq*4, n0);      // rows rowb+r, col n0
  }
}

__global__ __launch_bounds__(512) void prepF(
    const void* __restrict__ xraw, const void* __restrict__ wb,
    u16* __restrict__ Wg, u16* __restrict__ Wtg, u16* __restrict__ Pg,
    u16* __restrict__ Fb, u16* __restrict__ Fsw){
  __shared__ int s_bad;
  const int t = threadIdx.x, L = blockIdx.x;
  const int md = detect_md((const u16*)xraw, &s_bad, t, 512);
  u16* WgL = Wg  + (L<<14);
  u16* WtL = Wtg + (L<<14);
  u16* PL  = Pg  + (L<<14);
  u16* FbL = Fb  + (size_t)L*65536;

  // stage 0: convert layer-L W to bf16 + transpose (intra-kernel global
  // staging: each region is written before its first read; kernel-entry
  // acquire invalidates L1, __syncthreads drains vmcnt -> L2-visible)
  for(int j=t;j<16384;j+=512){
    u16 h = md ? ((const u16*)wb)[(L<<14)+j] : f2bf(((const float*)wb)[(L<<14)+j]);
    WgL[j] = h;
    WtL[(j&127)*U + (j>>7)] = h;
  }
  __syncthreads();
  // P = AFACT * Wt @ Wt^T
  g128(WtL, U, WtL, U, [&](f32x4 acc, int rowb, int n0){
    #pragma unroll
    for(int r=0;r<4;r++) PL[(rowb+r)*U + n0] = f2bf(AFACT*acc[r]);
  });
  __syncthreads();
  // S = INVC*(I - P + P@P) -> Fb00
  g128(PL, U, PL, U, [&](f32x4 acc, int rowb, int n0){
    #pragma unroll
    for(int r=0;r<4;r++){
      int row = rowb + r;
      FbL[row*256 + n0] = f2bf(INVC*(((row==n0)?1.0f:0.0f) - bf2f(PL[row*U+n0]) + acc[r]));
    }
  });
  __syncthreads();
  // Q = DT * S @ W^T -> Fb01 and Fb10^T
  g128(FbL, 256, WgL, U, [&](f32x4 acc, int rowb, int n0){
    #pragma unroll
    for(int r=0;r<4;r++){
      int row = rowb + r;
      u16 q = f2bf(DTc*acc[r]);
      FbL[row*256 + 128 + n0] = q;
      FbL[(128+n0)*256 + row] = q;
    }
  });
  __syncthreads();
  // R = DT * W @ Q -> Fb11
  g128(WgL, U, FbL + 128*256, 256, [&](f32x4 acc, int rowb, int n0){
    #pragma unroll
    for(int r=0;r<4;r++)
      FbL[(128+rowb+r)*256 + 128 + n0] = f2bf(DTc*acc[r]);
  });
  __syncthreads();
  // swizzle to fragment-major
  for(int i=t;i<8192;i+=512){
    int lanei = i & 63, kt = (i>>6)&7, c = (i>>9)&3, w = (i>>11)&3;
    int lni = lanei & 15, lqi = lanei >> 4;
    int row_n = 64*w + 16*c + lni;
    int col_k = kt*32 + lqi*8;
    *(bf16x8*)&Fsw[((size_t)L*8192 + i)*8] = *(const bf16x8*)&FbL[row_n*256 + col_k];
  }
}

// ---------------- main: 16 rows/block, 8 waves (2/SIMD), 1 barrier/step ------
__global__ __launch_bounds__(512,1) void mainK(
    const void* __restrict__ xraw, const void* __restrict__ w_in,
    const void* __restrict__ b_in, const void* __restrict__ bb,
    const bf16x8* __restrict__ Fsw, const void* __restrict__ w_out,
    const void* __restrict__ b_out, void* __restrict__ outraw){
  __shared__ u16 At[2][16*AST];          // ping-pong A tiles [T | r_u]
  __shared__ unsigned zh32[NL][16][66];  // stride 66 dwords: bank=(2row+p)%32 -> exact 2-way (free)
  __shared__ float zinu[16*U];
  __shared__ float bbL[NL*U];
  __shared__ float lg[16*12];
  __shared__ int s_bad;
  float* uout = (float*)&At[0][0];

  const int t = threadIdx.x;
  const int lane = t & 63, wid = t >> 6, ln = lane & 15, lq = lane >> 4;
  const int r0 = blockIdx.x * 16;

  const int md = detect_md((const u16*)xraw, &s_bad, t, 512);
  for(int i=t;i<NL*U;i+=512)
    bbL[i] = DTc * (md ? bf2f(((const u16*)bb)[i]) : ((const float*)bb)[i]);
  __syncthreads();

  // ---- phase 1: z1 = x @ w_in^T + b_in (w_in read directly, dual-mode) ----
  {
    const int n0 = 16*wid + ln;
    const u16*   wrb = (const u16*)w_in   + (size_t)n0*784;
    const float* wrf = (const float*)w_in + (size_t)n0*784;
    const u16*   xrb = (const u16*)xraw   + (size_t)(r0+ln)*784;
    const float* xrf = (const float*)xraw + (size_t)(r0+ln)*784;
    f32x4 acc = {0,0,0,0};
    const bf16x8 z8 = {0,0,0,0,0,0,0,0};
    if(md){
      #pragma unroll
      for(int kt=0; kt<24; ++kt){
        int k0 = kt*32 + lq*8;
        acc = MFMA16(*(const bf16x8*)(xrb + k0), *(const bf16x8*)(wrb + k0), acc);
      }
      { int k0 = 768 + lq*8;
        bf16x8 av = z8, bv = z8;
        if(lq < 2){ av = *(const bf16x8*)(xrb + k0); bv = *(const bf16x8*)(wrb + k0); }
        acc = MFMA16(av, bv, acc);
      }
    } else {
      #pragma unroll 4
      for(int kt=0; kt<24; ++kt){
        int k0 = kt*32 + lq*8;
        acc = MFMA16(ld8f(xrf + k0), ld8f(wrf + k0), acc);
      }
      { int k0 = 768 + lq*8;
        bf16x8 av = z8, bv = z8;
        if(lq < 2){ av = ld8f(xrf + k0); bv = ld8f(wrf + k0); }
        acc = MFMA16(av, bv, acc);
      }
    }
    float bi = md ? bf2f(((const u16*)b_in)[n0]) : ((const float*)b_in)[n0];
    #pragma unroll
    for(int r=0;r<4;r++) zinu[(lq*4+r)*U + n0] = acc[r] + bi;
  }
  __syncthreads();

  // ---- init: z-history, A-tile(0), r_u regs ----
  for(int i=t; i<NL*16*64; i+=512){
    int l = i>>10, row = (i>>6)&15, p = i & 63;
    int lo = 32*(p>>4) + (p&15);
    zh32[l][row][p] = ((unsigned)f2bf(zinu[row*U + lo + 16]) << 16) | f2bf(zinu[row*U + lo]);
  }
  float ru[2][4];
  if(wid < 4){
    #pragma unroll
    for(int cc=0;cc<2;cc++){
      int n = 32*wid + 16*cc + ln;
      #pragma unroll
      for(int r=0;r<4;r++){
        int row = lq*4 + r;
        At[0][row*AST + n] = f2bf((TENf + 1.0f) * fast_tanh(zinu[row*U + n]));
      }
    }
  } else {
    int w4 = wid - 4;
    #pragma unroll
    for(int cc=0;cc<2;cc++){
      int uc = 32*w4 + 16*cc + ln;
      #pragma unroll
      for(int r=0;r<4;r++){
        int row = lq*4 + r;
        float v = zinu[row*U + uc] + bbL[uc];
        ru[cc][r] = v;
        At[0][row*AST + 128 + uc] = f2bf(v);
      }
    }
  }
  // F fragment base for this wave (coalesced fragment-major)
  const bf16x8* fbase = Fsw + (wid>>1)*2048 + (wid&1)*1024 + lane;
  bf16x8 BfA[2][8], BfB[2][8];
  #pragma unroll
  for(int cc=0;cc<2;cc++){
    #pragma unroll
    for(int kt=0;kt<8;kt++) BfA[cc][kt] = fbase[cc*512 + kt*64];
  }
  __syncthreads();

#define STEPBODY(STEPV, BC, BN, CURC) { \
    const int l = (STEPV) & 7; \
    const int lnext = (l+1) & 7; \
    const bool last = ((STEPV) == NS*NL-1); \
    { const bf16x8* fp = fbase + lnext*8192; \
      _Pragma("unroll") \
      for(int cc=0;cc<2;cc++){ _Pragma("unroll") for(int kt=0;kt<8;kt++) BN[cc][kt] = fp[cc*512 + kt*64]; } } \
    bf16x8 at8[8]; \
    _Pragma("unroll") \
    for(int kt=0;kt<8;kt++) at8[kt] = *(const bf16x8*)&At[CURC][ln*AST + kt*32 + lq*8]; \
    float th[2][4]; \
    if(wid < 4 && !last){ \
      _Pragma("unroll") \
      for(int r=0;r<4;r++){ \
        unsigned pk = zh32[lnext][lq*4 + r][16*wid + ln]; \
        th[0][r] = TENf * fast_tanh(bf2f((u16)(pk & 0xffff))); \
        th[1][r] = TENf * fast_tanh(bf2f((u16)(pk >> 16))); \
      } \
    } \
    f32x4 acc[2] = {{0,0,0,0},{0,0,0,0}}; \
    _Pragma("unroll") \
    for(int kt=0;kt<8;kt++){ \
      acc[0] = MFMA16(at8[kt], BC[0][kt], acc[0]); \
      acc[1] = MFMA16(at8[kt], BC[1][kt], acc[1]); \
    } \
    if(wid < 4){ \
      if(!last){ \
        const bool wrap = (l == 7); \
        _Pragma("unroll") \
        for(int cc=0;cc<2;cc++){ \
          int n = 32*wid + 16*cc + ln; \
          _Pragma("unroll") \
          for(int r=0;r<4;r++){ \
            int row = lq*4 + r; \
            float base = wrap ? fast_tanh(zinu[row*U + n]) : acc[cc][r]; \
            At[1-(CURC)][row*AST + n] = f2bf(th[cc][r] + base); \
          } \
        } \
      } \
    } else { \
      int w4 = wid - 4; \
      _Pragma("unroll") \
      for(int r=0;r<4;r++){ \
        int row = lq*4 + r; \
        int uc0 = 32*w4 + ln; \
        float yu0 = ru[0][r] - acc[0][r]; \
        float yu1 = ru[1][r] - acc[1][r]; \
        zh32[l][row][16*w4 + ln] = ((unsigned)f2bf(yu1)<<16) | f2bf(yu0); \
        if(last){ \
          uout[row*U + uc0]      = zinu[row*U + uc0]      + bbL[7*U + uc0]      - acc[0][r]; \
          uout[row*U + uc0 + 16] = zinu[row*U + uc0 + 16] + bbL[7*U + uc0 + 16] - acc[1][r]; \
        } else if(l == 7){ \
          float rn0 = zinu[row*U + uc0]      + bbL[uc0]; \
          float rn1 = zinu[row*U + uc0 + 16] + bbL[uc0 + 16]; \
          ru[0][r] = rn0; ru[1][r] = rn1; \
          At[1-(CURC)][row*AST + 128 + uc0]      = f2bf(rn0); \
          At[1-(CURC)][row*AST + 128 + uc0 + 16] = f2bf(rn1); \
        } else { \
          float rn0 = yu0 + bbL[(l+1)*U + uc0]; \
          float rn1 = yu1 + bbL[(l+1)*U + uc0 + 16]; \
          ru[0][r] = rn0; ru[1][r] = rn1; \
          At[1-(CURC)][row*AST + 128 + uc0]      = f2bf(rn0); \
          At[1-(CURC)][row*AST + 128 + uc0 + 16] = f2bf(rn1); \
        } \
      } \
    } \
    lgkm_barrier(); \
  }

  for(int sp=0; sp<NS*NL; sp+=2){
    STEPBODY(sp,   BfA, BfB, 0)
    STEPBODY(sp+1, BfB, BfA, 1)
  }
#undef STEPBODY

  // ---- logits + softmax (w_out/b_out read directly, dual-mode) ----
  if(t < 160){
    int mm = t/10, o = t - mm*10;
    float a = md ? bf2f(((const u16*)b_out)[o]) : ((const float*)b_out)[o];
    if(md){
      const u16* wo = (const u16*)w_out + o*U;
      for(int k=0;k<U;k++) a += uout[mm*U + k]*bf2f(wo[k]);
    } else {
      const float* wo = (const float*)w_out + o*U;
      for(int k=0;k<U;k++) a += uout[mm*U + k]*wo[k];
    }
    lg[mm*12 + o] = a;
  }
  __syncthreads();
  if(t < 16){
    float mx = -1e30f;
    for(int o=0;o<10;o++) mx = fmaxf(mx, lg[t*12 + o]);
    float e[10]; float sum = 0.0f;
    for(int o=0;o<10;o++){ e[o] = __expf(lg[t*12 + o] - mx); sum += e[o]; }
    float inv = 1.0f / sum;
    for(int o=0;o<10;o++){
      float pv = e[o]*inv;
      if(md) ((u16*)outraw)[(size_t)(r0 + t)*10 + o] = f2bf(pv);
      else   ((float*)outraw)[(size_t)(r0 + t)*10 + o] = pv;
    }
  }
}

extern "C" void kernel_launch(void* const* d_in, const int* in_sizes, int n_in,
                              void* d_out, int out_size, void* d_ws, size_t ws_size,
                              hipStream_t stream) {
  char* p = (char*)d_ws;
  u16* Fb      = (u16*)p;  p += (size_t)8*256*256*2;   // 1 MB
  u16* Fsw     = (u16*)p;  p += (size_t)8*256*256*2;   // 1 MB
  u16* Wg      = (u16*)p;  p += (size_t)8*128*128*2;   // 256 KB
  u16* Wtg     = (u16*)p;  p += (size_t)8*128*128*2;
  u16* Pg      = (u16*)p;  p += (size_t)8*128*128*2;

  prepF<<<8, 512, 0, stream>>>(d_in[0], d_in[3], Wg, Wtg, Pg, Fb, Fsw);
  mainK<<<BATCH/16, 512, 0, stream>>>(d_in[0], d_in[1], d_in[2], d_in[4],
                                      (const bf16x8*)Fsw, d_in[5], d_in[6], d_out);
}

// Round 2
// 237.073 us; speedup vs baseline: 1.0349x; 1.0349x over previous
//
#include <hip/hip_runtime.h>

#define U 128
#define BATCH 2048
#define NL 8
#define NS 8                       /* NS=15 vs 10 bit-identical -> contraction <=0.36; NS=8 residual <1e-3 */
#define DTc 0.1f
#define TENf 10.0f                 /* DT/EPS */
#define INVC (1.0f/11.0f)          /* 1/(1+DT/EPS) */
#define AFACT (0.01f/11.0f)        /* DT^2 / c */
#define AST 266                    /* A-tile LDS stride (u16); 133 dwords -> bank 5*ln+4*lq, ~2-way */

typedef unsigned short u16;
typedef __attribute__((ext_vector_type(8))) short bf16x8;
typedef __attribute__((ext_vector_type(4))) float f32x4;
#define MFMA16(a,b,c) __builtin_amdgcn_mfma_f32_16x16x32_bf16(a,b,c,0,0,0)

__device__ __forceinline__ float bf2f(u16 h){ return __uint_as_float(((unsigned int)h)<<16); }
__device__ __forceinline__ u16 f2bf(float f){
  unsigned int u = __float_as_uint(f);
  u += 0x7FFFu + ((u >> 16) & 1u);
  return (u16)(u >> 16);
}
__device__ __forceinline__ float fast_tanh(float x){
  float e = __expf(2.0f*x);
  return 1.0f - __fdividef(2.0f, e + 1.0f);
}
__device__ __forceinline__ int detect_md(const u16* x, int* s_bad, int t, int nthr){
  if(t==0) *s_bad = 0;
  __syncthreads();
  int f=0;
  for(int i=t;i<4096;i+=nthr){ float v = bf2f(x[i]); if(!(fabsf(v)<16.0f)) f=1; }
  if(f) atomicOr(s_bad,1);
  __syncthreads();
  return *s_bad ? 0 : 1;   // 1 = bf16 inputs
}
__device__ __forceinline__ bf16x8 ld8f(const float* p){
  float4 f0 = *(const float4*)p, f1 = *(const float4*)(p+4);
  bf16x8 v;
  v[0]=(short)f2bf(f0.x); v[1]=(short)f2bf(f0.y); v[2]=(short)f2bf(f0.z); v[3]=(short)f2bf(f0.w);
  v[4]=(short)f2bf(f1.x); v[5]=(short)f2bf(f1.y); v[6]=(short)f2bf(f1.z); v[7]=(short)f2bf(f1.w);
  return v;
}
// LDS-only barrier: does NOT drain vmcnt, so F-prefetch global loads stay in
// flight across the per-step barrier. Only LDS crosses waves in the main loop.
__device__ __forceinline__ void lgkm_barrier(){
  __builtin_amdgcn_sched_barrier(0);
  asm volatile("s_waitcnt lgkmcnt(0)\n\ts_barrier" ::: "memory");
  __builtin_amdgcn_sched_barrier(0);
}

// 128x128x128 GEMM, 512 thr: wave wid owns rows wid*16..+16, c-loop over all
// 128 cols. Same (row,col,kt) accumulation chains as the old tile16 -> bits
// identical. getA/getB return the bf16x8 fragment at (row, k0).
template<typename GETA, typename GETB, typename EPI>
__device__ __forceinline__ void gemm128(GETA getA, GETB getB, EPI epi){
  const int lane = threadIdx.x & 63, wid = threadIdx.x >> 6;
  const int ln = lane & 15, lq = lane >> 4;
  bf16x8 af[4];
  #pragma unroll
  for(int kt=0;kt<4;kt++) af[kt] = getA(wid*16 + ln, kt*32 + lq*8);
  #pragma unroll 2
  for(int c=0;c<8;c++){
    const int n0 = c*16 + ln;
    f32x4 acc = {0,0,0,0};
    #pragma unroll
    for(int kt=0;kt<4;kt++) acc = MFMA16(af[kt], getB(n0, kt*32 + lq*8), acc);
    epi(acc, wid*16 + lq*4, n0);      // rows rowb+r (r=0..3), col n0
  }
}

// ---------------- prepF: LDS-resident per-layer chain, 8 blocks --------------
// conv -> P -> S -> Q^T -> (swiz F00/F01/F10) -> R -> (swiz F11).
// Zero global intermediates, zero cross-block deps. Bit-identical to the old
// 6-kernel chain (same fragment decomposition, same f2bf rounding points).
__global__ __launch_bounds__(512) void prepF(
    const void* __restrict__ xraw, const void* __restrict__ wb,
    u16* __restrict__ Fsw){
  __shared__ u16 buf0[128*128];   // 32 KB
  __shared__ u16 buf1[128*128];   // 32 KB
  __shared__ int s_bad;
  const int t = threadIdx.x, L = blockIdx.x;
  const int md = detect_md((const u16*)xraw, &s_bad, t, 512);
  const u16*   wbb = (const u16*)wb   + ((size_t)L<<14);
  const float* wbf = (const float*)wb + ((size_t)L<<14);

  auto g0 = [&](int row,int k0)->bf16x8{ return *(const bf16x8*)&buf0[row*U + k0]; };
  auto g1 = [&](int row,int k0)->bf16x8{ return *(const bf16x8*)&buf1[row*U + k0]; };
  auto gW = [&](int row,int k0)->bf16x8{
    if(md) return *(const bf16x8*)&wbb[row*U + k0];
    return ld8f(wbf + row*U + k0);
  };

  // stage 0: Wt into buf0 (Wt[k][n] = W[n][k], f2bf'd)
  for(int j=t;j<16384;j+=512){
    u16 h = md ? wbb[j] : f2bf(wbf[j]);
    buf0[(j&127)*U + (j>>7)] = h;
  }
  __syncthreads();
  // P = AFACT * Wt @ Wt^T  -> buf1
  gemm128(g0, g0, [&](f32x4 acc, int rowb, int n0){
    #pragma unroll
    for(int r=0;r<4;r++) buf1[(rowb+r)*U + n0] = f2bf(AFACT*acc[r]);
  });
  __syncthreads();
  // S = INVC*(I - P + P@P)  -> buf0 (reads buf1 only)
  gemm128(g1, g1, [&](f32x4 acc, int rowb, int n0){
    #pragma unroll
    for(int r=0;r<4;r++){
      int row = rowb + r;
      buf0[row*U + n0] = f2bf(INVC*(((row==n0)?1.0f:0.0f) - bf2f(buf1[row*U+n0]) + acc[r]));
    }
  });
  __syncthreads();
  // Q = DT * S @ W^T  -> store Q^T into buf1 (overwrites P)
  gemm128(g0, gW, [&](f32x4 acc, int rowb, int n0){
    #pragma unroll
    for(int r=0;r<4;r++) buf1[n0*U + (rowb+r)] = f2bf(DTc*acc[r]);
  });
  __syncthreads();
  // swizzle F00 (from S=buf0), F10 (from Q^T=buf1 rows), F01 (Q^T cols, scalar)
  for(int i=t;i<8192;i+=512){
    int lanei = i & 63, kt = (i>>6)&7, c = (i>>9)&3, w = (i>>11)&3;
    int lni = lanei & 15, lqi = lanei >> 4;
    int row_n = 64*w + 16*c + lni;
    int col_k = kt*32 + lqi*8;
    if(w < 2){
      if(kt < 4){
        *(bf16x8*)&Fsw[((size_t)L*8192+i)*8] = *(const bf16x8*)&buf0[row_n*U + col_k];
      } else {
        bf16x8 v;
        #pragma unroll
        for(int m=0;m<8;m++) v[m] = (short)buf1[(col_k-128+m)*U + row_n];
        *(bf16x8*)&Fsw[((size_t)L*8192+i)*8] = v;
      }
    } else if(kt < 4){
      *(bf16x8*)&Fsw[((size_t)L*8192+i)*8] = *(const bf16x8*)&buf1[(row_n-128)*U + col_k];
    }
  }
  __syncthreads();
  // R = DT * W @ Q = DT * W @ (Q^T)^T  -> buf0 (overwrites S; F00 already out)
  gemm128(gW, g1, [&](f32x4 acc, int rowb, int n0){
    #pragma unroll
    for(int r=0;r<4;r++) buf0[(rowb+r)*U + n0] = f2bf(DTc*acc[r]);
  });
  __syncthreads();
  // swizzle F11 (from R=buf0)
  for(int ii=t; ii<2048; ii+=512){
    int lanei = ii & 63, kt = 4 + ((ii>>6)&3), c = (ii>>8)&3, w = 2 + ((ii>>10)&1);
    int i = (w<<11)|(c<<9)|(kt<<6)|lanei;
    int lni = lanei & 15, lqi = lanei >> 4;
    int row_n = 64*w + 16*c + lni;
    int col_k = kt*32 + lqi*8;
    *(bf16x8*)&Fsw[((size_t)L*8192+i)*8] = *(const bf16x8*)&buf0[(row_n-128)*U + (col_k-128)];
  }
}

// ---------------- main: 16 rows/block, 8 waves (2/SIMD), 1 barrier/step ------
__global__ __launch_bounds__(512,1) void mainK(
    const void* __restrict__ xraw, const void* __restrict__ w_in,
    const void* __restrict__ b_in, const void* __restrict__ bb,
    const bf16x8* __restrict__ Fsw, const void* __restrict__ w_out,
    const void* __restrict__ b_out, void* __restrict__ outraw){
  __shared__ u16 At[2][16*AST];          // ping-pong A tiles [T | r_u]
  __shared__ unsigned zh32[NL][16][66];
  __shared__ float zinu[16*U];
  __shared__ float bbL[NL*U];
  __shared__ float lg[16*12];
  __shared__ int s_bad;
  float* uout = (float*)&At[0][0];

  const int t = threadIdx.x;
  const int lane = t & 63, wid = t >> 6, ln = lane & 15, lq = lane >> 4;
  const int r0 = blockIdx.x * 16;

  const int md = detect_md((const u16*)xraw, &s_bad, t, 512);
  for(int i=t;i<NL*U;i+=512)
    bbL[i] = DTc * (md ? bf2f(((const u16*)bb)[i]) : ((const float*)bb)[i]);
  __syncthreads();

  // ---- phase 1: z1 = x @ w_in^T + b_in (w_in read directly, dual-mode) ----
  {
    const int n0 = 16*wid + ln;
    const u16*   wrb = (const u16*)w_in   + (size_t)n0*784;
    const float* wrf = (const float*)w_in + (size_t)n0*784;
    const u16*   xrb = (const u16*)xraw   + (size_t)(r0+ln)*784;
    const float* xrf = (const float*)xraw + (size_t)(r0+ln)*784;
    f32x4 acc = {0,0,0,0};
    const bf16x8 z8 = {0,0,0,0,0,0,0,0};
    if(md){
      #pragma unroll
      for(int kt=0; kt<24; ++kt){
        int k0 = kt*32 + lq*8;
        acc = MFMA16(*(const bf16x8*)(xrb + k0), *(const bf16x8*)(wrb + k0), acc);
      }
      { int k0 = 768 + lq*8;
        bf16x8 av = z8, bv = z8;
        if(lq < 2){ av = *(const bf16x8*)(xrb + k0); bv = *(const bf16x8*)(wrb + k0); }
        acc = MFMA16(av, bv, acc);
      }
    } else {
      #pragma unroll 4
      for(int kt=0; kt<24; ++kt){
        int k0 = kt*32 + lq*8;
        acc = MFMA16(ld8f(xrf + k0), ld8f(wrf + k0), acc);
      }
      { int k0 = 768 + lq*8;
        bf16x8 av = z8, bv = z8;
        if(lq < 2){ av = ld8f(xrf + k0); bv = ld8f(wrf + k0); }
        acc = MFMA16(av, bv, acc);
      }
    }
    float bi = md ? bf2f(((const u16*)b_in)[n0]) : ((const float*)b_in)[n0];
    #pragma unroll
    for(int r=0;r<4;r++) zinu[(lq*4+r)*U + n0] = acc[r] + bi;
  }
  __syncthreads();

  // ---- init: z-history, A-tile(0), r_u regs ----
  for(int i=t; i<NL*16*64; i+=512){
    int l = i>>10, row = (i>>6)&15, p = i & 63;
    int lo = 32*(p>>4) + (p&15);
    zh32[l][row][p] = ((unsigned)f2bf(zinu[row*U + lo + 16]) << 16) | f2bf(zinu[row*U + lo]);
  }
  float ru[2][4];
  if(wid < 4){
    #pragma unroll
    for(int cc=0;cc<2;cc++){
      int n = 32*wid + 16*cc + ln;
      #pragma unroll
      for(int r=0;r<4;r++){
        int row = lq*4 + r;
        At[0][row*AST + n] = f2bf((TENf + 1.0f) * fast_tanh(zinu[row*U + n]));
      }
    }
  } else {
    int w4 = wid - 4;
    #pragma unroll
    for(int cc=0;cc<2;cc++){
      int uc = 32*w4 + 16*cc + ln;
      #pragma unroll
      for(int r=0;r<4;r++){
        int row = lq*4 + r;
        float v = zinu[row*U + uc] + bbL[uc];
        ru[cc][r] = v;
        At[0][row*AST + 128 + uc] = f2bf(v);
      }
    }
  }
  // F fragment base for this wave (coalesced fragment-major); NT loads: F has
  // zero L1 reuse (1 MB stream/step vs 32 KB L1), skip the L1 allocate.
  const bf16x8* fbase = Fsw + (wid>>1)*2048 + (wid&1)*1024 + lane;
  bf16x8 BfA[2][8], BfB[2][8];
  #pragma unroll
  for(int cc=0;cc<2;cc++){
    #pragma unroll
    for(int kt=0;kt<8;kt++) BfA[cc][kt] = __builtin_nontemporal_load(&fbase[cc*512 + kt*64]);
  }
  __syncthreads();

#define STEPBODY(STEPV, BC, BN, CURC) { \
    const int l = (STEPV) & 7; \
    const int lnext = (l+1) & 7; \
    const bool last = ((STEPV) == NS*NL-1); \
    { const bf16x8* fp = fbase + lnext*8192; \
      _Pragma("unroll") \
      for(int cc=0;cc<2;cc++){ _Pragma("unroll") for(int kt=0;kt<8;kt++) BN[cc][kt] = __builtin_nontemporal_load(&fp[cc*512 + kt*64]); } } \
    bf16x8 at8[8]; \
    _Pragma("unroll") \
    for(int kt=0;kt<8;kt++) at8[kt] = *(const bf16x8*)&At[CURC][ln*AST + kt*32 + lq*8]; \
    float th[2][4]; \
    if(wid < 4 && !last){ \
      _Pragma("unroll") \
      for(int r=0;r<4;r++){ \
        unsigned pk = zh32[lnext][lq*4 + r][16*wid + ln]; \
        th[0][r] = TENf * fast_tanh(bf2f((u16)(pk & 0xffff))); \
        th[1][r] = TENf * fast_tanh(bf2f((u16)(pk >> 16))); \
      } \
    } \
    f32x4 acc[2] = {{0,0,0,0},{0,0,0,0}}; \
    _Pragma("unroll") \
    for(int kt=0;kt<8;kt++){ \
      acc[0] = MFMA16(at8[kt], BC[0][kt], acc[0]); \
      acc[1] = MFMA16(at8[kt], BC[1][kt], acc[1]); \
    } \
    if(wid < 4){ \
      if(!last){ \
        const bool wrap = (l == 7); \
        _Pragma("unroll") \
        for(int cc=0;cc<2;cc++){ \
          int n = 32*wid + 16*cc + ln; \
          _Pragma("unroll") \
          for(int r=0;r<4;r++){ \
            int row = lq*4 + r; \
            float base = wrap ? fast_tanh(zinu[row*U + n]) : acc[cc][r]; \
            At[1-(CURC)][row*AST + n] = f2bf(th[cc][r] + base); \
          } \
        } \
      } \
    } else { \
      int w4 = wid - 4; \
      _Pragma("unroll") \
      for(int r=0;r<4;r++){ \
        int row = lq*4 + r; \
        int uc0 = 32*w4 + ln; \
        float yu0 = ru[0][r] - acc[0][r]; \
        float yu1 = ru[1][r] - acc[1][r]; \
        zh32[l][row][16*w4 + ln] = ((unsigned)f2bf(yu1)<<16) | f2bf(yu0); \
        if(last){ \
          uout[row*U + uc0]      = zinu[row*U + uc0]      + bbL[7*U + uc0]      - acc[0][r]; \
          uout[row*U + uc0 + 16] = zinu[row*U + uc0 + 16] + bbL[7*U + uc0 + 16] - acc[1][r]; \
        } else if(l == 7){ \
          float rn0 = zinu[row*U + uc0]      + bbL[uc0]; \
          float rn1 = zinu[row*U + uc0 + 16] + bbL[uc0 + 16]; \
          ru[0][r] = rn0; ru[1][r] = rn1; \
          At[1-(CURC)][row*AST + 128 + uc0]      = f2bf(rn0); \
          At[1-(CURC)][row*AST + 128 + uc0 + 16] = f2bf(rn1); \
        } else { \
          float rn0 = yu0 + bbL[(l+1)*U + uc0]; \
          float rn1 = yu1 + bbL[(l+1)*U + uc0 + 16]; \
          ru[0][r] = rn0; ru[1][r] = rn1; \
          At[1-(CURC)][row*AST + 128 + uc0]      = f2bf(rn0); \
          At[1-(CURC)][row*AST + 128 + uc0 + 16] = f2bf(rn1); \
        } \
      } \
    } \
    lgkm_barrier(); \
  }

  for(int sp=0; sp<NS*NL; sp+=2){
    STEPBODY(sp,   BfA, BfB, 0)
    STEPBODY(sp+1, BfB, BfA, 1)
  }
#undef STEPBODY

  // ---- logits + softmax (w_out/b_out read directly, dual-mode) ----
  if(t < 160){
    int mm = t/10, o = t - mm*10;
    float a = md ? bf2f(((const u16*)b_out)[o]) : ((const float*)b_out)[o];
    if(md){
      const u16* wo = (const u16*)w_out + o*U;
      for(int k=0;k<U;k++) a += uout[mm*U + k]*bf2f(wo[k]);
    } else {
      const float* wo = (const float*)w_out + o*U;
      for(int k=0;k<U;k++) a += uout[mm*U + k]*wo[k];
    }
    lg[mm*12 + o] = a;
  }
  __syncthreads();
  if(t < 16){
    float mx = -1e30f;
    for(int o=0;o<10;o++) mx = fmaxf(mx, lg[t*12 + o]);
    float e[10]; float sum = 0.0f;
    for(int o=0;o<10;o++){ e[o] = __expf(lg[t*12 + o] - mx); sum += e[o]; }
    float inv = 1.0f / sum;
    for(int o=0;o<10;o++){
      float pv = e[o]*inv;
      if(md) ((u16*)outraw)[(size_t)(r0 + t)*10 + o] = f2bf(pv);
      else   ((float*)outraw)[(size_t)(r0 + t)*10 + o] = pv;
    }
  }
}

extern "C" void kernel_launch(void* const* d_in, const int* in_sizes, int n_in,
                              void* d_out, int out_size, void* d_ws, size_t ws_size,
                              hipStream_t stream) {
  u16* Fsw = (u16*)d_ws;   // 8 layers x 256x256 bf16 fragment-major = 1 MB

  prepF<<<8, 512, 0, stream>>>(d_in[0], d_in[3], Fsw);
  mainK<<<BATCH/16, 512, 0, stream>>>(d_in[0], d_in[1], d_in[2], d_in[4],
                                      (const bf16x8*)Fsw, d_in[5], d_in[6], d_out);
}

// Round 4
// 203.217 us; speedup vs baseline: 1.2073x; 1.1666x over previous
//
#include <hip/hip_runtime.h>

#define U 128
#define BATCH 2048
#define NL 8
#define NS 8                       /* NS=15 vs 10 bit-identical -> contraction <=0.36; NS=8 residual <1e-3 */
#define DTc 0.1f
#define TENf 10.0f                 /* DT/EPS */
#define INVC (1.0f/11.0f)          /* 1/(1+DT/EPS) */
#define AFACT (0.01f/11.0f)        /* DT^2 / c */
#define AST 264                    /* A-tile LDS stride (u16); 132 dwords -> b128 reads conflict-free */

typedef unsigned short u16;
typedef __attribute__((ext_vector_type(8))) short bf16x8;
typedef __attribute__((ext_vector_type(4))) float f32x4;
#define MFMA16(a,b,c) __builtin_amdgcn_mfma_f32_16x16x32_bf16(a,b,c,0,0,0)

__device__ __forceinline__ float bf2f(u16 h){ return __uint_as_float(((unsigned int)h)<<16); }
__device__ __forceinline__ u16 f2bf(float f){
  unsigned int u = __float_as_uint(f);
  u += 0x7FFFu + ((u >> 16) & 1u);
  return (u16)(u >> 16);
}
__device__ __forceinline__ float fast_tanh(float x){
  float e = __expf(2.0f*x);
  return 1.0f - __fdividef(2.0f, e + 1.0f);
}
__device__ __forceinline__ int detect_md(const u16* x, int* s_bad, int t, int nthr){
  if(t==0) *s_bad = 0;
  __syncthreads();
  int f=0;
  for(int i=t;i<4096;i+=nthr){ float v = bf2f(x[i]); if(!(fabsf(v)<16.0f)) f=1; }
  if(f) atomicOr(s_bad,1);
  __syncthreads();
  return *s_bad ? 0 : 1;   // 1 = bf16 inputs
}
__device__ __forceinline__ bf16x8 ld8f(const float* p){
  float4 f0 = *(const float4*)p, f1 = *(const float4*)(p+4);
  bf16x8 v;
  v[0]=(short)f2bf(f0.x); v[1]=(short)f2bf(f0.y); v[2]=(short)f2bf(f0.z); v[3]=(short)f2bf(f0.w);
  v[4]=(short)f2bf(f1.x); v[5]=(short)f2bf(f1.y); v[6]=(short)f2bf(f1.z); v[7]=(short)f2bf(f1.w);
  return v;
}
// LDS-only barrier: does NOT drain vmcnt, so F-prefetch global loads stay in
// flight across the per-step barrier. Only LDS crosses waves in the main loop.
__device__ __forceinline__ void lgkm_barrier(){
  __builtin_amdgcn_sched_barrier(0);
  asm volatile("s_waitcnt lgkmcnt(0)\n\ts_barrier" ::: "memory");
  __builtin_amdgcn_sched_barrier(0);
}

// ---------------- s1: convert W + transpose, 128 blocks ----------------------
__global__ __launch_bounds__(256) void convK(
    const void* __restrict__ xraw, const void* __restrict__ wb,
    u16* __restrict__ Wg, u16* __restrict__ Wtg){
  __shared__ int s_bad;
  const int t = threadIdx.x;
  const int md = detect_md((const u16*)xraw, &s_bad, t, 256);
  const int g = blockIdx.x*256 + t, GS = gridDim.x*256;
  for(int i=g;i<131072;i+=GS){
    u16 h = md ? ((const u16*)wb)[i] : f2bf(((const float*)wb)[i]);
    Wg[i] = h;
    int L = i>>14, j = i & 16383;
    Wtg[(L<<14) + (j&127)*U + (j>>7)] = h;
  }
}

// block tile: 16 rows x 128 cols, K=128; A[m][k] (lda), B[n][k] (ldb). 256 thr.
template<typename EPI>
__device__ __forceinline__ void tile16(const u16* __restrict__ A, int lda,
                                       const u16* __restrict__ B, int ldb, EPI epi){
  const int lane = threadIdx.x & 63, w = threadIdx.x >> 6;
  const int ln = lane & 15, lq = lane >> 4;
  const int n0 = 32*w + ln, n1 = n0 + 16;
  bf16x8 af[4], b0[4], b1[4];
  #pragma unroll
  for(int kt=0;kt<4;kt++){
    af[kt] = *(const bf16x8*)&A[ln*lda + kt*32 + lq*8];
    b0[kt] = *(const bf16x8*)&B[n0*ldb + kt*32 + lq*8];
    b1[kt] = *(const bf16x8*)&B[n1*ldb + kt*32 + lq*8];
  }
  f32x4 a0 = {0,0,0,0}, a1 = {0,0,0,0};
  #pragma unroll
  for(int kt=0;kt<4;kt++){ a0 = MFMA16(af[kt], b0[kt], a0); a1 = MFMA16(af[kt], b1[kt], a1); }
  epi(a0, a1, n0, n1);
}

// ---------------- s2: P = AFACT * Wt @ Wt ------------------------------------
__global__ __launch_bounds__(256) void gemmP(const u16* __restrict__ Wtg, u16* __restrict__ Pg){
  const int L = blockIdx.x >> 3, mt = blockIdx.x & 7;
  const int lq = (threadIdx.x & 63) >> 4;
  const u16* WtL = Wtg + (L<<14);
  tile16(WtL + mt*16*U, U, WtL, U, [&](f32x4 a0, f32x4 a1, int n0, int n1){
    #pragma unroll
    for(int r=0;r<4;r++){
      int row = mt*16 + lq*4 + r;
      Pg[(L<<14) + row*U + n0] = f2bf(AFACT*a0[r]);
      Pg[(L<<14) + row*U + n1] = f2bf(AFACT*a1[r]);
    }
  });
}
// ---------------- s3: S = INVC(I - P + P@P) -> Fb00 --------------------------
__global__ __launch_bounds__(256) void gemmS(const u16* __restrict__ Pg, u16* __restrict__ Fb){
  const int L = blockIdx.x >> 3, mt = blockIdx.x & 7;
  const int lq = (threadIdx.x & 63) >> 4;
  const u16* PL = Pg + (L<<14);
  u16* FbL = Fb + (size_t)L*65536;
  tile16(PL + mt*16*U, U, PL, U, [&](f32x4 a0, f32x4 a1, int n0, int n1){
    #pragma unroll
    for(int r=0;r<4;r++){
      int row = mt*16 + lq*4 + r;
      FbL[row*256 + n0] = f2bf(INVC*(((row==n0)?1.0f:0.0f) - bf2f(PL[row*U+n0]) + a0[r]));
      FbL[row*256 + n1] = f2bf(INVC*(((row==n1)?1.0f:0.0f) - bf2f(PL[row*U+n1]) + a1[r]));
    }
  });
}
// ---------------- s4: Q = DT * S @ Wt -> Fb01, Fb10^T ------------------------
__global__ __launch_bounds__(256) void gemmQ(const u16* __restrict__ Fb, const u16* __restrict__ Wg,
                                             u16* __restrict__ FbW){
  const int L = blockIdx.x >> 3, mt = blockIdx.x & 7;
  const int lq = (threadIdx.x & 63) >> 4;
  const u16* FbL = Fb + (size_t)L*65536;
  u16* FbO = FbW + (size_t)L*65536;
  tile16(FbL + mt*16*256, 256, Wg + (L<<14), U, [&](f32x4 a0, f32x4 a1, int n0, int n1){
    #pragma unroll
    for(int r=0;r<4;r++){
      int row = mt*16 + lq*4 + r;
      u16 q0 = f2bf(DTc*a0[r]), q1 = f2bf(DTc*a1[r]);
      FbO[row*256 + 128 + n0] = q0;
      FbO[row*256 + 128 + n1] = q1;
      FbO[(128+n0)*256 + row] = q0;
      FbO[(128+n1)*256 + row] = q1;
    }
  });
}
// ---------------- s5: R = DT * W @ Q -> Fb11 ---------------------------------
__global__ __launch_bounds__(256) void gemmR(const u16* __restrict__ Wg, u16* __restrict__ Fb){
  const int L = blockIdx.x >> 3, mt = blockIdx.x & 7;
  const int lq = (threadIdx.x & 63) >> 4;
  u16* FbL = Fb + (size_t)L*65536;
  tile16(Wg + (L<<14) + mt*16*U, U, FbL + 128*256, 256, [&](f32x4 a0, f32x4 a1, int n0, int n1){
    #pragma unroll
    for(int r=0;r<4;r++){
      int row = mt*16 + lq*4 + r;
      FbL[(128+row)*256 + 128 + n0] = f2bf(DTc*a0[r]);
      FbL[(128+row)*256 + 128 + n1] = f2bf(DTc*a1[r]);
    }
  });
}
// ---------------- s6: swizzle F to fragment-major ----------------------------
__global__ __launch_bounds__(256) void swizK(const u16* __restrict__ Fb, u16* __restrict__ Fsw){
  const int L = blockIdx.x >> 3, part = blockIdx.x & 7;
  const u16* FbL = Fb + (size_t)L*65536;
  for(int i = part*1024 + threadIdx.x; i < (part+1)*1024; i += 256){
    int lanei = i & 63, kt = (i>>6)&7, c = (i>>9)&3, w = (i>>11)&3;
    int lni = lanei & 15, lqi = lanei >> 4;
    int row_n = 64*w + 16*c + lni;
    int col_k = kt*32 + lqi*8;
    *(bf16x8*)&Fsw[((size_t)L*8192 + i)*8] = *(const bf16x8*)&FbL[row_n*256 + col_k];
  }
}

// ---------------- main: 16 rows/block, 16 waves (4/SIMD), 1 barrier/step -----
// 1024 threads: each wave owns ONE 16-col fragment (col n = 16*wid + ln for
// the T-part waves 0..7; col 128 + 16*(wid-8) + ln for the v-part waves
// 8..15). Same MFMA (row,col,kt) chains as the 512-thr version -> bit-identical.
__global__ __launch_bounds__(1024,1) void mainK(
    const void* __restrict__ xraw, const void* __restrict__ w_in,
    const void* __restrict__ b_in, const void* __restrict__ bb,
    const bf16x8* __restrict__ Fsw, const void* __restrict__ w_out,
    const void* __restrict__ b_out, void* __restrict__ outraw){
  __shared__ u16 At[2][16*AST];          // ping-pong A tiles [T | r_u]
  __shared__ u16 zh16[NL][16][132];      // stride 66 dwords -> u16 ops conflict-free
  __shared__ float zinu[16*U];
  __shared__ float bbL[NL*U];
  __shared__ float lg[16*12];
  __shared__ int s_bad;
  float* uout = (float*)&At[0][0];

  const int t = threadIdx.x;
  const int lane = t & 63, wid = t >> 6, ln = lane & 15, lq = lane >> 4;
  const int r0 = blockIdx.x * 16;

  const int md = detect_md((const u16*)xraw, &s_bad, t, 1024);
  for(int i=t;i<NL*U;i+=1024)
    bbL[i] = DTc * (md ? bf2f(((const u16*)bb)[i]) : ((const float*)bb)[i]);
  __syncthreads();

  // ---- phase 1: z1 = x @ w_in^T + b_in (waves 0..7 only; cols 0..127) ----
  if(wid < 8){
    const int n0 = 16*wid + ln;
    const u16*   wrb = (const u16*)w_in   + (size_t)n0*784;
    const float* wrf = (const float*)w_in + (size_t)n0*784;
    const u16*   xrb = (const u16*)xraw   + (size_t)(r0+ln)*784;
    const float* xrf = (const float*)xraw + (size_t)(r0+ln)*784;
    f32x4 acc = {0,0,0,0};
    const bf16x8 z8 = {0,0,0,0,0,0,0,0};
    if(md){
      #pragma unroll
      for(int kt=0; kt<24; ++kt){
        int k0 = kt*32 + lq*8;
        acc = MFMA16(*(const bf16x8*)(xrb + k0), *(const bf16x8*)(wrb + k0), acc);
      }
      { int k0 = 768 + lq*8;
        bf16x8 av = z8, bv = z8;
        if(lq < 2){ av = *(const bf16x8*)(xrb + k0); bv = *(const bf16x8*)(wrb + k0); }
        acc = MFMA16(av, bv, acc);
      }
    } else {
      #pragma unroll 4
      for(int kt=0; kt<24; ++kt){
        int k0 = kt*32 + lq*8;
        acc = MFMA16(ld8f(xrf + k0), ld8f(wrf + k0), acc);
      }
      { int k0 = 768 + lq*8;
        bf16x8 av = z8, bv = z8;
        if(lq < 2){ av = ld8f(xrf + k0); bv = ld8f(wrf + k0); }
        acc = MFMA16(av, bv, acc);
      }
    }
    float bi = md ? bf2f(((const u16*)b_in)[n0]) : ((const float*)b_in)[n0];
    #pragma unroll
    for(int r=0;r<4;r++) zinu[(lq*4+r)*U + n0] = acc[r] + bi;
  }
  __syncthreads();

  // ---- init: z-history (u16, unpacked), A-tile(0), r_u regs ----
  for(int i=t; i<NL*16*128; i+=1024){
    int l = i>>11, row = (i>>7)&15, c = i & 127;
    zh16[l][row][c] = f2bf(zinu[row*U + c]);
  }
  float ru[4];
  if(wid < 8){
    const int n = 16*wid + ln;
    #pragma unroll
    for(int r=0;r<4;r++){
      int row = lq*4 + r;
      At[0][row*AST + n] = f2bf((TENf + 1.0f) * fast_tanh(zinu[row*U + n]));
    }
  } else {
    const int uc = 16*(wid-8) + ln;
    #pragma unroll
    for(int r=0;r<4;r++){
      int row = lq*4 + r;
      float v = zinu[row*U + uc] + bbL[uc];
      ru[r] = v;
      At[0][row*AST + 128 + uc] = f2bf(v);
    }
  }
  // F fragment base for this wave (coalesced fragment-major)
  const bf16x8* fbase = Fsw + (wid>>2)*2048 + (wid&3)*512 + lane;
  bf16x8 BfA[8], BfB[8];
  #pragma unroll
  for(int kt=0;kt<8;kt++) BfA[kt] = fbase[kt*64];
  __syncthreads();

#define STEPBODY(STEPV, BC, BN, CURC) { \
    const int l = (STEPV) & 7; \
    const int lnext = (l+1) & 7; \
    const bool last = ((STEPV) == NS*NL-1); \
    { const bf16x8* fp = fbase + lnext*8192; \
      _Pragma("unroll") \
      for(int kt=0;kt<8;kt++) BN[kt] = fp[kt*64]; } \
    bf16x8 at8[8]; \
    _Pragma("unroll") \
    for(int kt=0;kt<8;kt++) at8[kt] = *(const bf16x8*)&At[CURC][ln*AST + kt*32 + lq*8]; \
    float th[4]; \
    if(wid < 8 && !last){ \
      _Pragma("unroll") \
      for(int r=0;r<4;r++) th[r] = TENf * fast_tanh(bf2f(zh16[lnext][lq*4 + r][16*wid + ln])); \
    } \
    f32x4 acc = {0,0,0,0}; \
    _Pragma("unroll") \
    for(int kt=0;kt<8;kt++) acc = MFMA16(at8[kt], BC[kt], acc); \
    if(wid < 8){ \
      if(!last){ \
        const bool wrap = (l == 7); \
        const int n = 16*wid + ln; \
        _Pragma("unroll") \
        for(int r=0;r<4;r++){ \
          int row = lq*4 + r; \
          float base = wrap ? fast_tanh(zinu[row*U + n]) : acc[r]; \
          At[1-(CURC)][row*AST + n] = f2bf(th[r] + base); \
        } \
      } \
    } else { \
      const int uc0 = 16*(wid-8) + ln; \
      _Pragma("unroll") \
      for(int r=0;r<4;r++){ \
        int row = lq*4 + r; \
        float yu = ru[r] - acc[r]; \
        zh16[l][row][uc0] = f2bf(yu); \
        if(last){ \
          uout[row*U + uc0] = zinu[row*U + uc0] + bbL[7*U + uc0] - acc[r]; \
        } else if(l == 7){ \
          float rn = zinu[row*U + uc0] + bbL[uc0]; \
          ru[r] = rn; \
          At[1-(CURC)][row*AST + 128 + uc0] = f2bf(rn); \
        } else { \
          float rn = yu + bbL[(l+1)*U + uc0]; \
          ru[r] = rn; \
          At[1-(CURC)][row*AST + 128 + uc0] = f2bf(rn); \
        } \
      } \
    } \
    lgkm_barrier(); \
  }

  for(int sp=0; sp<NS*NL; sp+=2){
    STEPBODY(sp,   BfA, BfB, 0)
    STEPBODY(sp+1, BfB, BfA, 1)
  }
#undef STEPBODY

  // ---- logits + softmax (w_out/b_out read directly, dual-mode) ----
  if(t < 160){
    int mm = t/10, o = t - mm*10;
    float a = md ? bf2f(((const u16*)b_out)[o]) : ((const float*)b_out)[o];
    if(md){
      const u16* wo = (const u16*)w_out + o*U;
      for(int k=0;k<U;k++) a += uout[mm*U + k]*bf2f(wo[k]);
    } else {
      const float* wo = (const float*)w_out + o*U;
      for(int k=0;k<U;k++) a += uout[mm*U + k]*wo[k];
    }
    lg[mm*12 + o] = a;
  }
  __syncthreads();
  if(t < 16){
    float mx = -1e30f;
    for(int o=0;o<10;o++) mx = fmaxf(mx, lg[t*12 + o]);
    float e[10]; float sum = 0.0f;
    for(int o=0;o<10;o++){ e[o] = __expf(lg[t*12 + o] - mx); sum += e[o]; }
    float inv = 1.0f / sum;
    for(int o=0;o<10;o++){
      float pv = e[o]*inv;
      if(md) ((u16*)outraw)[(size_t)(r0 + t)*10 + o] = f2bf(pv);
      else   ((float*)outraw)[(size_t)(r0 + t)*10 + o] = pv;
    }
  }
}

extern "C" void kernel_launch(void* const* d_in, const int* in_sizes, int n_in,
                              void* d_out, int out_size, void* d_ws, size_t ws_size,
                              hipStream_t stream) {
  char* p = (char*)d_ws;
  u16* Fb      = (u16*)p;  p += (size_t)8*256*256*2;   // 1 MB
  u16* Fsw     = (u16*)p;  p += (size_t)8*256*256*2;   // 1 MB
  u16* Wg      = (u16*)p;  p += (size_t)8*128*128*2;   // 256 KB
  u16* Wtg     = (u16*)p;  p += (size_t)8*128*128*2;
  u16* Pg      = (u16*)p;  p += (size_t)8*128*128*2;

  convK<<<128, 256, 0, stream>>>(d_in[0], d_in[3], Wg, Wtg);
  gemmP<<<64, 256, 0, stream>>>(Wtg, Pg);
  gemmS<<<64, 256, 0, stream>>>(Pg, Fb);
  gemmQ<<<64, 256, 0, stream>>>(Fb, Wg, Fb);
  gemmR<<<64, 256, 0, stream>>>(Wg, Fb);
  swizK<<<64, 256, 0, stream>>>(Fb, Fsw);
  mainK<<<BATCH/16, 1024, 0, stream>>>(d_in[0], d_in[1], d_in[2], d_in[4],
                                       (const bf16x8*)Fsw, d_in[5], d_in[6], d_out);
}